// Round 1
// baseline (4397.455 us; speedup 1.0000x reference)
//
#include <hip/hip_runtime.h>
#include <stdint.h>

using u16 = unsigned short;
typedef unsigned int u32;
typedef __attribute__((ext_vector_type(4))) float f32x4;
typedef __attribute__((ext_vector_type(8))) short short8;

typedef const __attribute__((address_space(1))) u32* gas_ptr;
typedef __attribute__((address_space(3))) u32* las_ptr;

// ---------- bf16 helpers (bit-level, RNE) ----------
__device__ __forceinline__ u16 f2bf_u(float f) {
    u32 u = __builtin_bit_cast(u32, f);
    u32 r = 0x7fffu + ((u >> 16) & 1u);
    return (u16)((u + r) >> 16);
}
__device__ __forceinline__ float bfu2f(u16 h) {
    u32 u = ((u32)h) << 16;
    return __builtin_bit_cast(float, u);
}
__device__ __forceinline__ void split2(float v, u16& hi, u16& lo) {
    hi = f2bf_u(v);
    lo = f2bf_u(v - bfu2f(hi));   // exact residual, captures 8 more mantissa bits
}

__device__ __forceinline__ void gload16(const void* g, void* l) {
    __builtin_amdgcn_global_load_lds((gas_ptr)g, (las_ptr)l, 16, 0, 0);
}

// ---------- GEMM-BT (both operands K-contiguous), 128x128 tile, BK=32 ----------
// C[row][col] = sum_k A[row][k] * B[col][k], with split-3 phases:
//   ph0: Ahi*Bhi, ph1: Alo*Bhi, ph2: Ahi*Blo   (phases==1 -> plain Ahi*Bhi)
// EPI 0: h = relu(acc+aux[col]) -> split write (out0=hi,out1=lo), row-major [M][N]
// EPI 1: feat = acc+aux[col] -> split scatter to [b][col][c] (b=row>>9,c=row&511)
// EPI 2: tempT fp32 row-major write (scores; scale applied later per-row)
// EPI 3: fp32 row-major write with batch stride (preLN)
template<int EPI>
__global__ __launch_bounds__(256)
void gemm_bt(const u16* __restrict__ Ahi, const u16* __restrict__ Alo,
             const u16* __restrict__ Bhi, const u16* __restrict__ Blo,
             int K, int N, int phases,
             const float* __restrict__ aux,
             void* __restrict__ out0, void* __restrict__ out1,
             size_t strideA, size_t strideB, size_t strideO)
{
    __shared__ u16 As[128 * 32];
    __shared__ u16 Bs[128 * 32];

    const int t = threadIdx.x;
    const int w = t >> 6;
    const int l = t & 63;
    const int brow = blockIdx.y * 128;
    const int bcol = blockIdx.x * 128;
    const int z = blockIdx.z;

    const int srow = l >> 2;        // staging: 4 lanes per 64B row
    const int scol = (l & 3) * 8;   // bf16 elems (16B chunks)

    f32x4 acc[4][4];
    const f32x4 zero = {0.f, 0.f, 0.f, 0.f};
#pragma unroll
    for (int i = 0; i < 4; ++i)
#pragma unroll
        for (int j = 0; j < 4; ++j) acc[i][j] = zero;

    const int wr = w >> 1;
    const int wc = w & 1;
    const int lr = l & 15;
    const int kh = (l >> 4) * 8;

    for (int ph = 0; ph < phases; ++ph) {
        const u16* Ap = ((ph == 1) ? Alo : Ahi) + (size_t)z * strideA;
        const u16* Bp = ((ph == 2) ? Blo : Bhi) + (size_t)z * strideB;
        for (int kk = 0; kk < K; kk += 32) {
            __syncthreads();
#pragma unroll
            for (int c = 0; c < 2; ++c) {
                const int r = w * 32 + c * 16;  // wave-uniform LDS base row
                gload16(Ap + (size_t)(brow + r + srow) * K + (kk + scol), &As[r * 32]);
                gload16(Bp + (size_t)(bcol + r + srow) * K + (kk + scol), &Bs[r * 32]);
            }
            __syncthreads();
            short8 a[4], b[4];
#pragma unroll
            for (int m = 0; m < 4; ++m)
                a[m] = *(const short8*)&As[(wr * 64 + m * 16 + lr) * 32 + kh];
#pragma unroll
            for (int n = 0; n < 4; ++n)
                b[n] = *(const short8*)&Bs[(wc * 64 + n * 16 + lr) * 32 + kh];
#pragma unroll
            for (int m = 0; m < 4; ++m)
#pragma unroll
                for (int n = 0; n < 4; ++n)
                    acc[m][n] = __builtin_amdgcn_mfma_f32_16x16x32_bf16(a[m], b[n], acc[m][n], 0, 0, 0);
        }
    }

#pragma unroll
    for (int m = 0; m < 4; ++m)
#pragma unroll
        for (int n = 0; n < 4; ++n)
#pragma unroll
            for (int j = 0; j < 4; ++j) {
                const int row = brow + wr * 64 + m * 16 + (l >> 4) * 4 + j;
                const int col = bcol + wc * 64 + n * 16 + (l & 15);
                float v = acc[m][n][j];
                if (EPI == 0) {
                    v += aux[col];
                    v = fmaxf(v, 0.f);
                    u16 hi, lo; split2(v, hi, lo);
                    ((u16*)out0)[(size_t)row * N + col] = hi;
                    ((u16*)out1)[(size_t)row * N + col] = lo;
                } else if (EPI == 1) {
                    v += aux[col];
                    const int bb = row >> 9, cc = row & 511;
                    const size_t idx = ((size_t)bb * N + col) * 512 + cc;
                    u16 hi, lo; split2(v, hi, lo);
                    ((u16*)out0)[idx] = hi;
                    ((u16*)out1)[idx] = lo;
                } else if (EPI == 2) {
                    ((float*)out0)[(size_t)row * N + col] = v;
                } else {
                    ((float*)out0)[(size_t)z * strideO + (size_t)row * N + col] = v;
                }
            }
}

// ---------- elementwise split fp32 -> (hi,lo) bf16 ----------
__global__ void split_k(const float* __restrict__ in, u16* __restrict__ hi,
                        u16* __restrict__ lo, size_t n4)
{
    size_t i = blockIdx.x * (size_t)blockDim.x + threadIdx.x;
    const size_t stride = (size_t)gridDim.x * blockDim.x;
    for (; i < n4; i += stride) {
        const float4 v = ((const float4*)in)[i];
        ushort4 h, l;
        split2(v.x, h.x, l.x);
        split2(v.y, h.y, l.y);
        split2(v.z, h.z, l.z);
        split2(v.w, h.w, l.w);
        ((ushort4*)hi)[i] = h;
        ((ushort4*)lo)[i] = l;
    }
}

// ---------- plain fp32 -> bf16 convert ----------
__global__ void conv_bf16_k(const float* __restrict__ in, u16* __restrict__ out, size_t n4)
{
    size_t i = blockIdx.x * (size_t)blockDim.x + threadIdx.x;
    const size_t stride = (size_t)gridDim.x * blockDim.x;
    for (; i < n4; i += stride) {
        const float4 v = ((const float4*)in)[i];
        ushort4 o;
        o.x = f2bf_u(v.x); o.y = f2bf_u(v.y); o.z = f2bf_u(v.z); o.w = f2bf_u(v.w);
        ((ushort4*)out)[i] = o;
    }
}

// ---------- x (B,512,4096) -> xt (B,4096,512) with hi/lo split ----------
__global__ void transpose_split_x(const float* __restrict__ x,
                                  u16* __restrict__ xt_hi, u16* __restrict__ xt_lo)
{
    __shared__ float tile[32][33];
    const int b = blockIdx.z;
    const int n0 = blockIdx.x * 32;
    const int c0 = blockIdx.y * 32;
    const int tx = threadIdx.x, ty = threadIdx.y;   // block (32,8)
#pragma unroll
    for (int k = 0; k < 4; ++k)
        tile[ty + 8 * k][tx] = x[((size_t)b * 512 + c0 + ty + 8 * k) * 4096 + n0 + tx];
    __syncthreads();
#pragma unroll
    for (int k = 0; k < 4; ++k) {
        const float v = tile[tx][ty + 8 * k];       // [c_local][n_local]
        u16 hi, lo; split2(v, hi, lo);
        const size_t idx = ((size_t)b * 4096 + n0 + ty + 8 * k) * 512 + c0 + tx;
        xt_hi[idx] = hi;
        xt_lo[idx] = lo;
    }
}

// ---------- scale vector: s[n] = exp(min(ls[n], log(100))) ----------
__global__ void scale_prep(const float* __restrict__ ls, float* __restrict__ s)
{
    const int i = blockIdx.x * blockDim.x + threadIdx.x;
    if (i < 4096) s[i] = expf(fminf(ls[i], 4.605170185988092f));
}

// ---------- row softmax of tempT (4096 cols), row-scale s[m], write bf16 P ----------
__global__ __launch_bounds__(256)
void softmax_rows(const float* __restrict__ T, const float* __restrict__ s, u16* __restrict__ P)
{
    const int m = blockIdx.x;
    const int t = threadIdx.x;
    const float sc = s[m];
    const float* row = T + (size_t)m * 4096;
    float v[16];
    float mx = -3.402823e38f;
#pragma unroll
    for (int i = 0; i < 16; ++i) {
        v[i] = row[t + 256 * i] * sc;
        mx = fmaxf(mx, v[i]);
    }
#pragma unroll
    for (int o = 32; o; o >>= 1) mx = fmaxf(mx, __shfl_xor(mx, o, 64));
    __shared__ float sm[4], ss[4];
    if ((t & 63) == 0) sm[t >> 6] = mx;
    __syncthreads();
    mx = fmaxf(fmaxf(sm[0], sm[1]), fmaxf(sm[2], sm[3]));
    float sum = 0.f;
#pragma unroll
    for (int i = 0; i < 16; ++i) {
        v[i] = expf(v[i] - mx);
        sum += v[i];
    }
#pragma unroll
    for (int o = 32; o; o >>= 1) sum += __shfl_xor(sum, o, 64);
    if ((t & 63) == 0) ss[t >> 6] = sum;
    __syncthreads();
    sum = (ss[0] + ss[1]) + (ss[2] + ss[3]);
    const float inv = 1.f / sum;
#pragma unroll
    for (int i = 0; i < 16; ++i)
        P[(size_t)m * 4096 + t + 256 * i] = f2bf_u(v[i] * inv);
}

// ---------- LayerNorm rows of 4096 ----------
__global__ __launch_bounds__(256)
void ln_rows(const float* __restrict__ X, const float* __restrict__ gw,
             const float* __restrict__ gb, float* __restrict__ out)
{
    const int r = blockIdx.x;
    const int t = threadIdx.x;
    const float* row = X + (size_t)r * 4096;
    float v[16];
    float s1 = 0.f, s2 = 0.f;
#pragma unroll
    for (int i = 0; i < 16; ++i) {
        v[i] = row[t + 256 * i];
        s1 += v[i];
        s2 += v[i] * v[i];
    }
#pragma unroll
    for (int o = 32; o; o >>= 1) {
        s1 += __shfl_xor(s1, o, 64);
        s2 += __shfl_xor(s2, o, 64);
    }
    __shared__ float m1[4], m2[4];
    if ((t & 63) == 0) { m1[t >> 6] = s1; m2[t >> 6] = s2; }
    __syncthreads();
    s1 = (m1[0] + m1[1]) + (m1[2] + m1[3]);
    s2 = (m2[0] + m2[1]) + (m2[2] + m2[3]);
    const float mu = s1 * (1.f / 4096.f);
    const float var = s2 * (1.f / 4096.f) - mu * mu;
    const float rs = rsqrtf(var + 1e-5f);
#pragma unroll
    for (int i = 0; i < 16; ++i) {
        const int n = t + 256 * i;
        out[(size_t)r * 4096 + n] = (v[i] - mu) * rs * gw[n] + gb[n];
    }
}

extern "C" void kernel_launch(void* const* d_in, const int* in_sizes, int n_in,
                              void* d_out, int out_size, void* d_ws, size_t ws_size,
                              hipStream_t stream)
{
    const float* x  = (const float*)d_in[0];
    const float* fe = (const float*)d_in[1];
    const float* w1 = (const float*)d_in[2];
    const float* b1 = (const float*)d_in[3];
    const float* w2 = (const float*)d_in[4];
    const float* b2 = (const float*)d_in[5];
    const float* ls = (const float*)d_in[6];
    const float* nw = (const float*)d_in[7];
    const float* nb = (const float*)d_in[8];
    float* out = (float*)d_out;
    char* ws = (char*)d_ws;

    // Workspace plan (bytes). Region reuse relies on stream ordering:
    //   [0,536.9M)   feature/w1 splits        (dead after GEMM1)
    //   [536.9,604M) h hi/lo                  (dead after GEMM2)
    //   reuse of [0,...): w2, ft, xt, xbf, tempT, P_all, preLN
    if (ws_size < 637550592ull) return;  // ~608 MB needed; signals via absmax=5.53

    u16*  fhi  = (u16*) (ws + 0ull);
    u16*  flo  = (u16*) (ws + 134217728ull);
    u16*  w1hi = (u16*) (ws + 268435456ull);
    u16*  w1lo = (u16*) (ws + 402653184ull);
    u16*  hhi  = (u16*) (ws + 536870912ull);
    u16*  hlo  = (u16*) (ws + 570425344ull);
    u16*  w2hi = (u16*) (ws + 0ull);
    u16*  w2lo = (u16*) (ws + 33554432ull);
    u16*  fthi = (u16*) (ws + 67108864ull);
    u16*  ftlo = (u16*) (ws + 100663296ull);
    u16*  xthi = (u16*) (ws + 134217728ull);
    u16*  xtlo = (u16*) (ws + 167772160ull);
    u16*  xbf  = (u16*) (ws + 201326592ull);
    float* tt  = (float*)(ws + 234881024ull);   // one-batch scores, fp32
    u16*  pall = (u16*) (ws + 301989888ull);    // softmaxed P, all batches, bf16
    float* pre = (float*)(ws + 570425344ull);   // pre-LN output, fp32
    float* sv  = (float*)(ws + 637534208ull);   // scale vector

    // 1. split feature and fc1_w
    split_k<<<2048, 256, 0, stream>>>(fe, fhi, flo, (size_t)16777216);
    split_k<<<2048, 256, 0, stream>>>(w1, w1hi, w1lo, (size_t)16777216);

    // 2. GEMM1: h = relu(feature @ fc1_w^T + b1)   M=4096 N=4096 K=16384, split-3
    gemm_bt<0><<<dim3(32, 32, 1), 256, 0, stream>>>(fhi, flo, w1hi, w1lo,
        16384, 4096, 3, b1, hhi, hlo, 0, 0, 0);

    // 3. split fc2_w (reuses feature region — safe after GEMM1 in stream order)
    split_k<<<2048, 256, 0, stream>>>(w2, w2hi, w2lo, (size_t)4194304);

    // 4. GEMM2: feat = h @ fc2_w^T + b2, scattered to ft[b][n][c]
    gemm_bt<1><<<dim3(32, 32, 1), 256, 0, stream>>>(hhi, hlo, w2hi, w2lo,
        4096, 4096, 3, b2, fthi, ftlo, 0, 0, 0);

    // 5. x transforms (regions dead after GEMM1) + scale vector
    transpose_split_x<<<dim3(128, 16, 8), dim3(32, 8), 0, stream>>>(x, xthi, xtlo);
    conv_bf16_k<<<2048, 256, 0, stream>>>(x, xbf, (size_t)4194304);
    scale_prep<<<16, 256, 0, stream>>>(ls, sv);

    // 6. per batch: scores GEMM (split-3, K=512) + row softmax -> P
    for (int b = 0; b < 8; ++b) {
        const size_t xo = (size_t)b * 4096 * 512;
        gemm_bt<2><<<dim3(32, 32, 1), 256, 0, stream>>>(xthi + xo, xtlo + xo,
            fthi + xo, ftlo + xo, 512, 4096, 3, nullptr, tt, nullptr, 0, 0, 0);
        softmax_rows<<<4096, 256, 0, stream>>>(tt, sv, pall + (size_t)b * 16777216);
    }

    // 7. GEMM4: out_pre[b][c][m] = sum_n xbf[b][c][n] * P[b][m][n]  (plain bf16)
    gemm_bt<3><<<dim3(32, 4, 8), 256, 0, stream>>>(xbf, nullptr, pall, nullptr,
        4096, 4096, 1, nullptr, pre, nullptr,
        (size_t)512 * 4096, (size_t)4096 * 4096, (size_t)512 * 4096);

    // 8. LayerNorm
    ln_rows<<<4096, 256, 0, stream>>>(pre, nw, nb, out);
}

// Round 3
// 4385.159 us; speedup vs baseline: 1.0028x; 1.0028x over previous
//
#include <hip/hip_runtime.h>
#include <stdint.h>

using u16 = unsigned short;
typedef unsigned int u32;
typedef __attribute__((ext_vector_type(4))) float f32x4;
typedef __attribute__((ext_vector_type(8))) short short8;

typedef const __attribute__((address_space(1))) u32* gas_ptr;
typedef __attribute__((address_space(3))) u32* las_ptr;

// ---------- bf16 helpers (bit-level, RNE) ----------
__device__ __forceinline__ u16 f2bf_u(float f) {
    u32 u = __builtin_bit_cast(u32, f);
    u32 r = 0x7fffu + ((u >> 16) & 1u);
    return (u16)((u + r) >> 16);
}
__device__ __forceinline__ float bfu2f(u16 h) {
    u32 u = ((u32)h) << 16;
    return __builtin_bit_cast(float, u);
}
__device__ __forceinline__ void split2(float v, u16& hi, u16& lo) {
    hi = f2bf_u(v);
    lo = f2bf_u(v - bfu2f(hi));   // exact residual, ~16 mantissa bits total
}

__device__ __forceinline__ void gload16(const void* g, void* l) {
    __builtin_amdgcn_global_load_lds((gas_ptr)g, (las_ptr)l, 16, 0, 0);
}

// ---------- GEMM-BT (both operands K-contiguous), 128x128 tile, BK=32 ----------
// SPLIT=true: C[row][col] = sum_k (Ahi*Bhi + Alo*Bhi + Ahi*Blo)  (3 products,
//   one K-pass: stage all 4 tiles per K-step, 48 MFMA per barrier-pair)
// SPLIT=false: plain Ahi*Bhi.
// LDS chunk swizzle: slot (row, c) holds global 16B-chunk c ^ ((row>>1)&3).
// Staged via pre-swizzled GLOBAL source (LDS dest linear, global_load_lds rule);
// read with matching XOR. Lanes 0-15 then cover all 8 (row-parity × chunk)
// bank-groups exactly 2x -> conflict-free ds_read_b128.
// EPI 0: v=acc+aux[col]; relu; bf16 split write (out0=hi,out1=lo), [M][N]
// EPI 1: v=acc+aux[col]; bf16 split scatter to [b][col][c] (b=row>>9,c=row&511)
// EPI 2: fp32 row-major write (scores; per-row scale applied in softmax)
// EPI 3: fp32 write with batch stride (preLN)
template<int EPI, bool SPLIT>
__global__ __launch_bounds__(256)
void gemm_bt(const u16* __restrict__ Ah, const u16* __restrict__ Al,
             const u16* __restrict__ Bh, const u16* __restrict__ Bl,
             int K, int N,
             const float* __restrict__ aux,
             void* __restrict__ out0, void* __restrict__ out1,
             size_t strideA, size_t strideB, size_t strideO)
{
    __shared__ __align__(16) u16 As0[128 * 32];
    __shared__ __align__(16) u16 Bs0[128 * 32];
    __shared__ __align__(16) u16 As1[SPLIT ? 128 * 32 : 8];
    __shared__ __align__(16) u16 Bs1[SPLIT ? 128 * 32 : 8];

    const int t = threadIdx.x;
    const int w = t >> 6;
    const int l = t & 63;

    // XCD-chunked bijective swizzle (all grids have nwg % 8 == 0):
    // 128 consecutive swizzled ids share an XCD; same-brow blocks adjacent.
    const int gx = gridDim.x;
    const int nwg = gx * gridDim.y;
    const int orig = blockIdx.y * gx + blockIdx.x;
    const int swz = (orig & 7) * (nwg >> 3) + (orig >> 3);
    const int brow = (swz / gx) * 128;
    const int bcol = (swz % gx) * 128;
    const int z = blockIdx.z;

    const u16* A0 = Ah + (size_t)z * strideA;
    const u16* A1 = SPLIT ? (Al + (size_t)z * strideA) : nullptr;
    const u16* B0 = Bh + (size_t)z * strideB;
    const u16* B1 = SPLIT ? (Bl + (size_t)z * strideB) : nullptr;

    // staging: lane l covers row l>>2 (of 16), LDS chunk l&3;
    // global chunk for that slot = (l&3) ^ ((row>>1)&3) = (l&3) ^ ((l>>3)&3)
    const int srow = l >> 2;
    const int sca = ((l & 3) ^ ((l >> 3) & 3)) * 8;

    f32x4 acc[4][4];
    const f32x4 zero = {0.f, 0.f, 0.f, 0.f};
#pragma unroll
    for (int i = 0; i < 4; ++i)
#pragma unroll
        for (int j = 0; j < 4; ++j) acc[i][j] = zero;

    const int wr = w >> 1;
    const int wc = w & 1;
    const int lr = l & 15;
    // frag read: row R = base + (l&15), want global chunk g = l>>4;
    // slot chunk = g ^ ((R>>1)&3) = (l>>4) ^ (((l&15)>>1)&3)
    const int cr = ((l >> 4) ^ ((l >> 1) & 3)) * 8;

    for (int kk = 0; kk < K; kk += 32) {
        __syncthreads();
#pragma unroll
        for (int c = 0; c < 2; ++c) {
            const int r = w * 32 + c * 16;   // wave-uniform LDS base row
            const size_t ga = (size_t)(brow + r + srow) * K + (kk + sca);
            const size_t gb = (size_t)(bcol + r + srow) * K + (kk + sca);
            gload16(A0 + ga, &As0[r * 32]);
            gload16(B0 + gb, &Bs0[r * 32]);
            if constexpr (SPLIT) {
                gload16(A1 + ga, &As1[r * 32]);
                gload16(B1 + gb, &Bs1[r * 32]);
            }
        }
        __syncthreads();
        short8 ah[4], bh[4], al[4], bl[4];
#pragma unroll
        for (int m = 0; m < 4; ++m) {
            const int ro = (wr * 64 + m * 16 + lr) * 32 + cr;
            ah[m] = *(const short8*)&As0[ro];
            if constexpr (SPLIT) al[m] = *(const short8*)&As1[ro];
        }
#pragma unroll
        for (int n = 0; n < 4; ++n) {
            const int ro = (wc * 64 + n * 16 + lr) * 32 + cr;
            bh[n] = *(const short8*)&Bs0[ro];
            if constexpr (SPLIT) bl[n] = *(const short8*)&Bs1[ro];
        }
#pragma unroll
        for (int m = 0; m < 4; ++m)
#pragma unroll
            for (int n = 0; n < 4; ++n)
                acc[m][n] = __builtin_amdgcn_mfma_f32_16x16x32_bf16(ah[m], bh[n], acc[m][n], 0, 0, 0);
        if constexpr (SPLIT) {
#pragma unroll
            for (int m = 0; m < 4; ++m)
#pragma unroll
                for (int n = 0; n < 4; ++n) {
                    acc[m][n] = __builtin_amdgcn_mfma_f32_16x16x32_bf16(al[m], bh[n], acc[m][n], 0, 0, 0);
                    acc[m][n] = __builtin_amdgcn_mfma_f32_16x16x32_bf16(ah[m], bl[n], acc[m][n], 0, 0, 0);
                }
        }
    }

#pragma unroll
    for (int m = 0; m < 4; ++m)
#pragma unroll
        for (int n = 0; n < 4; ++n)
#pragma unroll
            for (int j = 0; j < 4; ++j) {
                const int row = brow + wr * 64 + m * 16 + (l >> 4) * 4 + j;
                const int col = bcol + wc * 64 + n * 16 + (l & 15);
                float v = acc[m][n][j];
                if (EPI == 0) {
                    v += aux[col];
                    v = fmaxf(v, 0.f);
                    u16 hi, lo; split2(v, hi, lo);
                    ((u16*)out0)[(size_t)row * N + col] = hi;
                    ((u16*)out1)[(size_t)row * N + col] = lo;
                } else if (EPI == 1) {
                    v += aux[col];
                    const int bb = row >> 9, cc = row & 511;
                    const size_t idx = ((size_t)bb * N + col) * 512 + cc;
                    u16 hi, lo; split2(v, hi, lo);
                    ((u16*)out0)[idx] = hi;
                    ((u16*)out1)[idx] = lo;
                } else if (EPI == 2) {
                    ((float*)out0)[(size_t)row * N + col] = v;
                } else {
                    ((float*)out0)[(size_t)z * strideO + (size_t)row * N + col] = v;
                }
            }
}

// ---------- elementwise split fp32 -> (hi,lo) bf16 ----------
__global__ void split_k(const float* __restrict__ in, u16* __restrict__ hi,
                        u16* __restrict__ lo, size_t n4)
{
    size_t i = blockIdx.x * (size_t)blockDim.x + threadIdx.x;
    const size_t stride = (size_t)gridDim.x * blockDim.x;
    for (; i < n4; i += stride) {
        const float4 v = ((const float4*)in)[i];
        ushort4 h, l;
        split2(v.x, h.x, l.x);
        split2(v.y, h.y, l.y);
        split2(v.z, h.z, l.z);
        split2(v.w, h.w, l.w);
        ((ushort4*)hi)[i] = h;
        ((ushort4*)lo)[i] = l;
    }
}

// ---------- plain fp32 -> bf16 convert ----------
__global__ void conv_bf16_k(const float* __restrict__ in, u16* __restrict__ out, size_t n4)
{
    size_t i = blockIdx.x * (size_t)blockDim.x + threadIdx.x;
    const size_t stride = (size_t)gridDim.x * blockDim.x;
    for (; i < n4; i += stride) {
        const float4 v = ((const float4*)in)[i];
        ushort4 o;
        o.x = f2bf_u(v.x); o.y = f2bf_u(v.y); o.z = f2bf_u(v.z); o.w = f2bf_u(v.w);
        ((ushort4*)out)[i] = o;
    }
}

// ---------- x (B,512,4096) -> xt (B,4096,512) with bf16 hi/lo split ----------
__global__ void transpose_split_x(const float* __restrict__ x,
                                  u16* __restrict__ xt_hi, u16* __restrict__ xt_lo)
{
    __shared__ float tile[32][33];
    const int b = blockIdx.z;
    const int n0 = blockIdx.x * 32;
    const int c0 = blockIdx.y * 32;
    const int tx = threadIdx.x, ty = threadIdx.y;   // block (32,8)
#pragma unroll
    for (int k = 0; k < 4; ++k)
        tile[ty + 8 * k][tx] = x[((size_t)b * 512 + c0 + ty + 8 * k) * 4096 + n0 + tx];
    __syncthreads();
#pragma unroll
    for (int k = 0; k < 4; ++k) {
        const float v = tile[tx][ty + 8 * k];       // [c_local][n_local]
        u16 hi, lo; split2(v, hi, lo);
        const size_t idx = ((size_t)b * 4096 + n0 + ty + 8 * k) * 512 + c0 + tx;
        xt_hi[idx] = hi;
        xt_lo[idx] = lo;
    }
}

// ---------- scale vector: s[n] = exp(min(ls[n], log(100))) ----------
__global__ void scale_prep(const float* __restrict__ ls, float* __restrict__ s)
{
    const int i = blockIdx.x * blockDim.x + threadIdx.x;
    if (i < 4096) s[i] = expf(fminf(ls[i], 4.605170185988092f));
}

// ---------- row softmax of tempT (4096 cols), row-scale s[m], write bf16 P ----------
__global__ __launch_bounds__(256)
void softmax_rows(const float* __restrict__ T, const float* __restrict__ s, u16* __restrict__ P)
{
    const int m = blockIdx.x;
    const int t = threadIdx.x;
    const float sc = s[m];
    const float* row = T + (size_t)m * 4096;
    float v[16];
    float mx = -3.402823e38f;
#pragma unroll
    for (int i = 0; i < 16; ++i) {
        v[i] = row[t + 256 * i] * sc;
        mx = fmaxf(mx, v[i]);
    }
#pragma unroll
    for (int o = 32; o; o >>= 1) mx = fmaxf(mx, __shfl_xor(mx, o, 64));
    __shared__ float sm[4], ss[4];
    if ((t & 63) == 0) sm[t >> 6] = mx;
    __syncthreads();
    mx = fmaxf(fmaxf(sm[0], sm[1]), fmaxf(sm[2], sm[3]));
    float sum = 0.f;
#pragma unroll
    for (int i = 0; i < 16; ++i) {
        v[i] = expf(v[i] - mx);
        sum += v[i];
    }
#pragma unroll
    for (int o = 32; o; o >>= 1) sum += __shfl_xor(sum, o, 64);
    if ((t & 63) == 0) ss[t >> 6] = sum;
    __syncthreads();
    sum = (ss[0] + ss[1]) + (ss[2] + ss[3]);
    const float inv = 1.f / sum;
#pragma unroll
    for (int i = 0; i < 16; ++i)
        P[(size_t)m * 4096 + t + 256 * i] = f2bf_u(v[i] * inv);
}

// ---------- LayerNorm rows of 4096 ----------
__global__ __launch_bounds__(256)
void ln_rows(const float* __restrict__ X, const float* __restrict__ gw,
             const float* __restrict__ gb, float* __restrict__ out)
{
    const int r = blockIdx.x;
    const int t = threadIdx.x;
    const float* row = X + (size_t)r * 4096;
    float v[16];
    float s1 = 0.f, s2 = 0.f;
#pragma unroll
    for (int i = 0; i < 16; ++i) {
        v[i] = row[t + 256 * i];
        s1 += v[i];
        s2 += v[i] * v[i];
    }
#pragma unroll
    for (int o = 32; o; o >>= 1) {
        s1 += __shfl_xor(s1, o, 64);
        s2 += __shfl_xor(s2, o, 64);
    }
    __shared__ float m1[4], m2[4];
    if ((t & 63) == 0) { m1[t >> 6] = s1; m2[t >> 6] = s2; }
    __syncthreads();
    s1 = (m1[0] + m1[1]) + (m1[2] + m1[3]);
    s2 = (m2[0] + m2[1]) + (m2[2] + m2[3]);
    const float mu = s1 * (1.f / 4096.f);
    const float var = s2 * (1.f / 4096.f) - mu * mu;
    const float rs = rsqrtf(var + 1e-5f);
#pragma unroll
    for (int i = 0; i < 16; ++i) {
        const int n = t + 256 * i;
        out[(size_t)r * 4096 + n] = (v[i] - mu) * rs * gw[n] + gb[n];
    }
}

extern "C" void kernel_launch(void* const* d_in, const int* in_sizes, int n_in,
                              void* d_out, int out_size, void* d_ws, size_t ws_size,
                              hipStream_t stream)
{
    const float* x  = (const float*)d_in[0];
    const float* fe = (const float*)d_in[1];
    const float* w1 = (const float*)d_in[2];
    const float* b1 = (const float*)d_in[3];
    const float* w2 = (const float*)d_in[4];
    const float* b2 = (const float*)d_in[5];
    const float* ls = (const float*)d_in[6];
    const float* nw = (const float*)d_in[7];
    const float* nb = (const float*)d_in[8];
    float* out = (float*)d_out;
    char* ws = (char*)d_ws;

    if (ws_size < 637550592ull) return;

    // Workspace plan (identical to round-1 PASSED layout; stream-order reuse):
    u16*  fhi  = (u16*) (ws + 0ull);
    u16*  flo  = (u16*) (ws + 134217728ull);
    u16*  w1hi = (u16*) (ws + 268435456ull);
    u16*  w1lo = (u16*) (ws + 402653184ull);
    u16*  hhi  = (u16*) (ws + 536870912ull);
    u16*  hlo  = (u16*) (ws + 570425344ull);
    u16*  w2hi = (u16*) (ws + 0ull);           // fe region dead after GEMM1
    u16*  w2lo = (u16*) (ws + 33554432ull);
    u16*  fthi = (u16*) (ws + 67108864ull);
    u16*  ftlo = (u16*) (ws + 100663296ull);
    u16*  xthi = (u16*) (ws + 134217728ull);
    u16*  xtlo = (u16*) (ws + 167772160ull);
    u16*  xbf  = (u16*) (ws + 201326592ull);
    float* tt  = (float*)(ws + 234881024ull);   // one-batch scores, fp32
    u16*  pall = (u16*) (ws + 301989888ull);    // P bf16, all batches
    float* pre = (float*)(ws + 570425344ull);   // pre-LN fp32 (h dead)
    float* sv  = (float*)(ws + 637534208ull);

    // 1. split feature and fc1_w
    split_k<<<2048, 256, 0, stream>>>(fe, fhi, flo, (size_t)16777216);
    split_k<<<2048, 256, 0, stream>>>(w1, w1hi, w1lo, (size_t)16777216);

    // 2. GEMM1: h = relu(feature @ fc1_w^T + b1), split-3 single K-pass
    gemm_bt<0, true><<<dim3(32, 32, 1), 256, 0, stream>>>(fhi, flo, w1hi, w1lo,
        16384, 4096, b1, hhi, hlo, 0, 0, 0);

    // 3. split fc2_w (fe region dead after GEMM1 in stream order)
    split_k<<<2048, 256, 0, stream>>>(w2, w2hi, w2lo, (size_t)4194304);

    // 4. GEMM2: feat = h @ fc2_w^T + b2, split scatter to ft[b][n][c]
    gemm_bt<1, true><<<dim3(32, 32, 1), 256, 0, stream>>>(hhi, hlo, w2hi, w2lo,
        4096, 4096, b2, fthi, ftlo, 0, 0, 0);

    // 5. x transforms + scale vector
    transpose_split_x<<<dim3(128, 16, 8), dim3(32, 8), 0, stream>>>(x, xthi, xtlo);
    conv_bf16_k<<<2048, 256, 0, stream>>>(x, xbf, (size_t)4194304);
    scale_prep<<<16, 256, 0, stream>>>(ls, sv);

    // 6. per batch: scores GEMM (split-3, K=512) + row softmax -> P
    for (int b = 0; b < 8; ++b) {
        const size_t o = (size_t)b * 4096 * 512;
        gemm_bt<2, true><<<dim3(32, 32, 1), 256, 0, stream>>>(xthi + o, xtlo + o,
            fthi + o, ftlo + o, 512, 4096, nullptr, tt, nullptr, 0, 0, 0);
        softmax_rows<<<4096, 256, 0, stream>>>(tt, sv, pall + (size_t)b * 16777216);
    }

    // 7. GEMM4: pre[b][c][m] = sum_n x[b][c][n] * P[b][m][n]   (plain bf16)
    gemm_bt<3, false><<<dim3(32, 4, 8), 256, 0, stream>>>(xbf, nullptr, pall, nullptr,
        4096, 4096, nullptr, pre, nullptr,
        (size_t)512 * 4096, (size_t)4096 * 4096, (size_t)512 * 4096);

    // 8. LayerNorm
    ln_rows<<<4096, 256, 0, stream>>>(pre, nw, nb, out);
}